// Round 11
// baseline (458.490 us; speedup 1.0000x reference)
//
#include <hip/hip_runtime.h>

typedef unsigned short u16;
typedef unsigned int u32;
typedef __attribute__((ext_vector_type(8))) __bf16 bf16x8;
typedef __attribute__((ext_vector_type(4))) __bf16 bf16x4;
typedef __attribute__((ext_vector_type(4))) float f32x4;

#define S_LEN 169

// ---------------- workspace layout (bytes)
// w2a: w2^T in MFMA A-frag layout: frag(rt,ks) 1KB blocks; elem (t,s):
//      ((rt*6+ks)*64 + ((s>>3)&3)*16 + (t&15))*16 + (s&7)*2, rt=t>>4, ks=s>>5
#define W2A_WS 0                          // 98304
#define WPK_WS 98304                      // bf16 frag-packed weights [3][1024][16B]
#define KE_WS  147456                     // bf16 [256][176][16] = 1441792
#define KV_WS  1589248
#define SG_WS  3031040
#define CNT_WS 4472832                    // u32 [256] fan-in counters

// ---------------- gs kernel LDS (50.8 KB -> 3 blocks/CU)
// phase A: staging [17][512] bf16 swz @0 (17408); raw [3][16][16] f32 @0 (3072)
// phase C overlays (staging dead):
#define SKE  0        // bf16 [169][16]
#define SKV  5632     // bf16 [169][16]
#define SGT  11264    // f32  [176][16] gate = sigmoid/denom
#define SKVT 22528    // bf16 [16][192] swz
#define SSS  28672    // f32  [12][16] segment sums
#define SOW  29696    // bf16 [64][40]
#define SRB  34816    // bf16 [128][40] (half of t-range at a time)
#define FLG  45056    // int flag
#define SGB  45072    // bf16 [169][16] sigmoid staging
#define GS_LDS 50816

// ---------------- K0: blocks 0..191 compute w2a (frag layout); 192..194 pack weights
__global__ __launch_bounds__(1024) void k0_kernel(
    const float* __restrict__ time_w,
    const float* __restrict__ time_alpha,
    const float* __restrict__ time_beta,
    const float* __restrict__ key_w,
    const float* __restrict__ value_w,
    const float* __restrict__ recep_w,
    char* __restrict__ ws)
{
    const int blk = blockIdx.x;
    if (blk >= 192) {
        const int m = blk - 192;
        const float* wmat = (m == 0) ? key_w : (m == 1) ? value_w : recep_w;
        const int g = threadIdx.x;   // 1024 granules of 8 f32, coalesced
        const float* src = wmat + g * 8;
        float4 f0 = *(const float4*)src;
        float4 f1 = *(const float4*)(src + 4);
        bf16x8 p;
        p[0]=(__bf16)f0.x; p[1]=(__bf16)f0.y; p[2]=(__bf16)f0.z; p[3]=(__bf16)f0.w;
        p[4]=(__bf16)f1.x; p[5]=(__bf16)f1.y; p[6]=(__bf16)f1.z; p[7]=(__bf16)f1.w;
        int hs = g >> 6, rem = g & 63, ks = rem >> 2, q = rem & 3;
        int fid = ks * 64 + q * 16 + hs;
        *(bf16x8*)(ws + WPK_WS + m * 16384 + fid * 16) = p;
        return;
    }
    __shared__ float tw[256];
    __shared__ float al[256];
    __shared__ float part[4][256];
    const int s = blk;
    const int t = threadIdx.x & 255;
    const int p = threadIdx.x >> 8;
    const u32 adr = (u32)(((( t >> 4) * 6 + (s >> 5)) * 64 + ((s >> 3) & 3) * 16 + (t & 15)) * 16
                          + (s & 7) * 2);
    if (s >= S_LEN) {                      // zero-pad s in [169,192)
        if (p == 0) *(u16*)(ws + W2A_WS + adr) = 0;
        return;
    }
    if (p == 0) { tw[t] = time_w[s * 256 + t]; al[t] = time_alpha[s * 256 + t]; }
    __syncthreads();
    const int u0 = p << 6;
    const int u1 = (u0 + 64 < t + 1) ? (u0 + 64) : (t + 1);
    float acc = 0.f;
    for (int u = u0; u < u1; ++u)
        acc = fmaf(tw[255 + u - t], al[u], acc);
    part[p][t] = acc;
    __syncthreads();
    if (p == 0) {
        __bf16 v = (__bf16)(time_beta[s * 256 + t] *
                            (part[0][t] + part[1][t] + part[2][t] + part[3][t]));
        *(u16*)(ws + W2A_WS + adr) = *(u16*)&v;
    }
}

// ---------------- GS: GEMM1 + pointwise + (last block per b) scan/wkv/out-proj
__global__ __launch_bounds__(192) void gs_kernel(
    const float* __restrict__ x,
    const float* __restrict__ key_b,
    const float* __restrict__ value_b,
    const float* __restrict__ recep_b,
    const float* __restrict__ out_w, const float* __restrict__ out_b,
    const float* __restrict__ gamma,
    char* __restrict__ ws,
    float* __restrict__ out)
{
    __shared__ __align__(16) char smem[GS_LDS];
    const int tid  = threadIdx.x;
    const int lane = tid & 63;
    const int wid  = tid >> 6;       // 0..2 -> matrices k/v/r
    const int q    = lane >> 4;
    const int hs   = lane & 15;
    const int blk  = blockIdx.x;
    const int b    = blk / 11;
    const int slab = blk - b * 11;
    const int t0   = slab * 16;
    const float* xb = x + (size_t)b * (S_LEN * 512);

    // ======== phase A: GEMM1 slab (identical structure to R10 g_kernel) ========
    bf16x8 bfrag[16];
    #pragma unroll
    for (int ks = 0; ks < 16; ++ks)
        bfrag[ks] = *(const bf16x8*)(ws + WPK_WS + wid * 16384 + (ks * 64 + lane) * 16);
    const float* bv = (wid == 0) ? key_b : (wid == 1) ? value_b : recep_b;
    const float bias = bv[hs];

    // stage rows t0-1 .. t0+15 (17 rows x 512 f32 = one contiguous 34 KB sweep)
    float4 st[12];
    int    sv[12];
    #pragma unroll
    for (int it = 0; it < 12; ++it) {
        int idx = tid + it * 192; if (idx > 2175) idx = 2175;
        int row = idx >> 7, c4 = idx & 127;
        int g   = t0 - 1 + row;
        sv[it]  = ((unsigned)g < (unsigned)S_LEN) ? 1 : 0;
        int gc  = g < 0 ? 0 : (g > S_LEN - 1 ? S_LEN - 1 : g);
        st[it]  = *(const float4*)(xb + (size_t)gc * 512 + c4 * 4);
    }
    #pragma unroll
    for (int it = 0; it < 12; ++it) {
        int idx = tid + it * 192; if (idx > 2175) idx = 2175;
        int row = idx >> 7, c4 = idx & 127;
        float4 f = st[it];
        if (!sv[it]) f = (float4){0.f, 0.f, 0.f, 0.f};
        bf16x4 p;
        p[0] = (__bf16)f.x; p[1] = (__bf16)f.y; p[2] = (__bf16)f.z; p[3] = (__bf16)f.w;
        u32 off = (u32)row * 1024 + ((((u32)c4) * 8u) ^ (((u32)(row & 7)) << 4));
        *(bf16x4*)(smem + off) = p;
    }
    __syncthreads();

    f32x4 acc = (f32x4){0.f, 0.f, 0.f, 0.f};
    #pragma unroll
    for (int ks = 0; ks < 16; ++ks) {
        int r = hs + ((ks < 8) ? 0 : 1);
        u32 off = (u32)r * 1024 + (((u32)(ks * 64 + q * 16)) ^ (((u32)(r & 7)) << 4));
        bf16x8 a = *(const bf16x8*)(smem + off);
        acc = __builtin_amdgcn_mfma_f32_16x16x32_bf16(a, bfrag[ks], acc, 0, 0, 0);
    }
    __syncthreads();

    float* raw = (float*)smem;
    #pragma unroll
    for (int rg = 0; rg < 4; ++rg)
        raw[wid * 256 + (q * 4 + rg) * 16 + hs] = acc[rg] + bias;
    __syncthreads();

    __bf16* keg = (__bf16*)(ws + KE_WS);
    __bf16* kvg = (__bf16*)(ws + KV_WS);
    __bf16* sgg = (__bf16*)(ws + SG_WS);
    for (int i = tid; i < 256; i += 192) {
        int tl = i >> 4, h = i & 15;
        int t  = t0 + tl;
        if (t < S_LEN) {
            float kk = fminf(fmaxf(raw[i], -60.f), 30.f);
            float ke = __expf(kk);
            size_t o = ((size_t)b * 176 + t) * 16 + h;
            keg[o] = (__bf16)ke;
            kvg[o] = (__bf16)(ke * raw[256 + i]);
            sgg[o] = (__bf16)(1.f / (1.f + __expf(-raw[512 + i])));
        }
    }

    // ======== phase B: fan-in (release -> count -> last block acquires) ========
    __threadfence();                       // release: all this block's ws writes visible
    __syncthreads();                       // all 3 waves' fences done
    if (tid == 0) {
        u32 old = atomicAdd((u32*)(ws + CNT_WS) + b, 1u);
        *(volatile int*)(smem + FLG) = (old == 10) ? 1 : 0;
    }
    __syncthreads();
    if (*(volatile int*)(smem + FLG) == 0) return;
    __threadfence();                       // acquire: other blocks' ws writes visible

    // ======== phase C: scan + wkv + out-proj for this b (192 threads) ========
    const float4* keb = (const float4*)(ws + KE_WS + (size_t)b * 5632);
    const float4* kvb = (const float4*)(ws + KV_WS + (size_t)b * 5632);
    const float4* sgb = (const float4*)(ws + SG_WS + (size_t)b * 5632);
    #pragma unroll
    for (int it = 0; it < 2; ++it) {
        int i = tid + it * 192;
        if (i < 338) {                      // 169 rows * 16 bf16 = 338 float4
            ((float4*)(smem + SKE))[i] = keb[i];
            ((float4*)(smem + SKV))[i] = kvb[i];
            ((float4*)(smem + SGB))[i] = sgb[i];
        }
    }
    for (int i = tid; i < 2560; i += 192) {  // owT [64][40], cols 16..39 zero
        int o = i / 40, c = i - o * 40;
        ((__bf16*)(smem + SOW))[i] = (c < 16) ? (__bf16)out_w[o * 16 + c] : (__bf16)0.f;
    }
    for (int i = tid; i < 368; i += 192) {   // kvT tail s in [169,192)
        int h2 = i & 15; int t = S_LEN + (i >> 4);
        u32 off = ((u32)(h2 * 384 + t * 2)) ^ (((u32)(h2 & 7)) << 4);
        *(__bf16*)(smem + SKVT + off) = (__bf16)0.f;
    }
    for (int i = tid; i < 2048; i += 192) {  // SRB pad cols 16..31 (stays zero both halves)
        int row = i >> 4, c = 16 + (i & 15);
        ((__bf16*)(smem + SRB))[row * 40 + c] = (__bf16)0.f;
    }
    __syncthreads();

    const __bf16* KEl = (const __bf16*)(smem + SKE);
    const __bf16* SGl = (const __bf16*)(smem + SGB);
    float* GATE = (float*)(smem + SGT);
    float* SEG  = (float*)(smem + SSS);
    const int h   = tid & 15;
    const int seg = tid >> 4;                // 0..11
    const int ts  = seg * 15;
    const int te  = (ts + 15 < S_LEN) ? ts + 15 : S_LEN;
    {
        float ssum = 0.f;
        for (int t = ts; t < te; ++t) ssum += (float)KEl[t * 16 + h];
        SEG[seg * 16 + h] = ssum;
    }
    __syncthreads();
    {
        float run = 0.f;
        for (int s2 = 0; s2 < seg; ++s2) run += SEG[s2 * 16 + h];  // broadcast reads
        for (int t = ts; t < te; ++t) {
            run += (float)KEl[t * 16 + h];                          // inclusive cumsum
            GATE[t * 16 + h] = (float)SGl[t * 16 + h] / run;
            u32 off = ((u32)(h * 384 + t * 2)) ^ (((u32)(h & 7)) << 4);
            *(u16*)(smem + SKVT + off) = ((const u16*)(smem + SKV))[t * 16 + h];
        }
    }
    __syncthreads();

    float obv[4];
    #pragma unroll
    for (int nt = 0; nt < 4; ++nt) obv[nt] = out_b[nt * 16 + hs];

    #pragma unroll
    for (int half = 0; half < 2; ++half) {
        // wkv tiles rt = half*8 + {wid, wid+3, wid+6} (<8)
        for (int rt8 = wid; rt8 < 8; rt8 += 3) {
            int rt = half * 8 + rt8;
            f32x4 wa = (f32x4){0.f, 0.f, 0.f, 0.f};
            #pragma unroll
            for (int ks = 0; ks < 6; ++ks) {
                int scol = ks * 32 + (q << 3);
                u32 boff = ((u32)(hs * 384 + scol * 2)) ^ (((u32)(hs & 7)) << 4);
                bf16x8 bfr = *(const bf16x8*)(smem + SKVT + boff);
                bf16x8 afr = *(const bf16x8*)(ws + W2A_WS + (u32)(((rt * 6 + ks) * 64 + lane) * 16));
                wa = __builtin_amdgcn_mfma_f32_16x16x32_bf16(afr, bfr, wa, 0, 0, 0);
            }
            #pragma unroll
            for (int rg = 0; rg < 4; ++rg) {
                int t = rt * 16 + (q << 2) + rg;
                float fac = (t < S_LEN) ? GATE[t * 16 + hs] : 0.5f;
                ((__bf16*)(smem + SRB))[(t - half * 128) * 40 + hs] = (__bf16)(wa[rg] * fac);
            }
        }
        __syncthreads();
        // out-proj for this half
        for (int mt8 = wid; mt8 < 8; mt8 += 3) {
            int mt = half * 8 + mt8;
            int lrow = mt8 * 16 + hs;
            bf16x8 afr = *(const bf16x8*)(smem + SRB + (u32)(lrow * 80 + (q << 4)));
            float gm[4];
            #pragma unroll
            for (int rg = 0; rg < 4; ++rg) gm[rg] = gamma[mt * 16 + (q << 2) + rg];
            #pragma unroll
            for (int nt = 0; nt < 4; ++nt) {
                int orow = nt * 16 + hs;
                bf16x8 bfr = *(const bf16x8*)(smem + SOW + (u32)(orow * 80 + (q << 4)));
                f32x4 zc = (f32x4){0.f, 0.f, 0.f, 0.f};
                f32x4 d = __builtin_amdgcn_mfma_f32_16x16x32_bf16(afr, bfr, zc, 0, 0, 0);
                #pragma unroll
                for (int rg = 0; rg < 4; ++rg) {
                    int t = mt * 16 + (q << 2) + rg;
                    out[(size_t)b * 16384 + (size_t)t * 64 + nt * 16 + hs] = (d[rg] + obv[nt]) * gm[rg];
                }
            }
        }
        __syncthreads();   // SRB reused by next half
    }
}

extern "C" void kernel_launch(void* const* d_in, const int* in_sizes, int n_in,
                              void* d_out, int out_size, void* d_ws, size_t ws_size,
                              hipStream_t stream) {
    const float* x          = (const float*)d_in[0];
    const float* time_w     = (const float*)d_in[1];
    const float* time_alpha = (const float*)d_in[2];
    const float* time_beta  = (const float*)d_in[3];
    const float* time_gamma = (const float*)d_in[4];
    const float* key_w      = (const float*)d_in[5];
    const float* key_b      = (const float*)d_in[6];
    const float* value_w    = (const float*)d_in[7];
    const float* value_b    = (const float*)d_in[8];
    const float* recep_w    = (const float*)d_in[9];
    const float* recep_b    = (const float*)d_in[10];
    const float* out_w      = (const float*)d_in[11];
    const float* out_b      = (const float*)d_in[12];
    char* ws = (char*)d_ws;

    hipMemsetAsync(ws + CNT_WS, 0, 1024, stream);   // fan-in counters
    k0_kernel<<<195, 1024, 0, stream>>>(time_w, time_alpha, time_beta,
                                        key_w, value_w, recep_w, ws);
    gs_kernel<<<2816, 192, 0, stream>>>(x, key_b, value_b, recep_b,
                                        out_w, out_b, time_gamma,
                                        ws, (float*)d_out);
}